// Round 11
// baseline (442.575 us; speedup 1.0000x reference)
//
#include <hip/hip_runtime.h>

#define IMG_W 1024
#define BATCH 32
#define NPIX (IMG_W * IMG_W)
#define STRIPE_COLS 256
#define TILE_ROWS 32
#define N_TILES (IMG_W / TILE_ROWS)              // 32
#define Y_BLOCKS ((BATCH * IMG_W) / STRIPE_COLS) // 128
#define X_BLOCKS ((BATCH * IMG_W) / 16)          // 2048

// Y-blocks (bid 0..127) first: one per CU early, X-blocks backfill.
__global__ __launch_bounds__(1024) void sgi_fused_kernel(const float* __restrict__ in,
                                                         float* __restrict__ out) {
    __shared__ float tile[TILE_ROWS][STRIPE_COLS]; // 32 KiB
    __shared__ float aux[4][STRIPE_COLS];          // 4 KiB

    const int bid = blockIdx.x;
    const int tid = threadIdx.x;

    if (bid < Y_BLOCKS) {
        // ---- Y: height cumsum (channel 1) via LDS-transposed tiles --------
        // Stripe = 256 cols x 1024 rows. Global reads AND writes are 1 KiB
        // contiguous per wave-instruction (64 lanes x float4 = one tile row);
        // the column-direction scan happens in LDS.
        const int b  = bid >> 2;                  // 4 stripes per image
        const int c0 = (bid & 3) * STRIPE_COLS;
        const float* ib = in  + (size_t)b * (2 * NPIX) + NPIX + c0;
        float*       ob = out + (size_t)b * (2 * NPIX) + NPIX + c0;

        const int c = tid & 255;                  // column owned in scan phase
        const int q = tid >> 8;                   // quarter (8 rows) of the tile

        // float4 slots for the two load/store sweeps (wave = one tile row).
        const int r0 = tid >> 6,          cc0 = (tid & 63) * 4;
        const int r1 = (tid + 1024) >> 6, cc1 = (tid & 63) * 4;

        float carry = 0.0f;                       // per-column, 4 replicas

        for (int t = 0; t < N_TILES; ++t) {
            const size_t rowbase = (size_t)t * TILE_ROWS;
            // P0: coalesced load (1 KiB per wave-instr)
            *(float4*)&tile[r0][cc0] = *(const float4*)(ib + (rowbase + r0) * IMG_W + cc0);
            *(float4*)&tile[r1][cc1] = *(const float4*)(ib + (rowbase + r1) * IMG_W + cc1);
            __syncthreads();
            // P2: serial scan of 8 rows of column c (2-way LDS aliasing: free)
            float p[8];
            float run = 0.0f;
            #pragma unroll
            for (int i = 0; i < 8; ++i) { run += tile[q * 8 + i][c]; p[i] = run; }
            aux[q][c] = run;
            __syncthreads();
            // P4: exclusive offset of this quarter + register carry update
            const float a0 = aux[0][c], a1 = aux[1][c], a2 = aux[2][c], a3 = aux[3][c];
            float qoff = carry;
            if (q > 0) qoff += a0;
            if (q > 1) qoff += a1;
            if (q > 2) qoff += a2;
            carry += a0 + a1 + a2 + a3;
            // P5: updated values back into tile
            #pragma unroll
            for (int i = 0; i < 8; ++i) tile[q * 8 + i][c] = p[i] + qoff;
            __syncthreads();
            // P7: coalesced store (1 KiB per wave-instr)
            *(float4*)(ob + (rowbase + r0) * IMG_W + cc0) = *(const float4*)&tile[r0][cc0];
            *(float4*)(ob + (rowbase + r1) * IMG_W + cc1) = *(const float4*)&tile[r1][cc1];
            __syncthreads();                      // tile reuse fence
        }
    } else {
        // ---- X: width cumsum (channel 0), one wave per row ----------------
        const int xbid = bid - Y_BLOCKS;          // 0..2047
        const int lane = tid & 63;
        const int wave = tid >> 6;
        const int row  = xbid * 16 + wave;
        const int b    = row >> 10;
        const int y    = row & (IMG_W - 1);

        const size_t base = (size_t)b * (2 * NPIX) + (size_t)y * IMG_W;
        const float4* ip = (const float4*)(in + base);
        float4*       op = (float4*)(out + base);

        float4 a[4];
        #pragma unroll
        for (int qq = 0; qq < 4; ++qq) a[qq] = ip[qq * 64 + lane];

        float carry = 0.0f;
        #pragma unroll
        for (int qq = 0; qq < 4; ++qq) {
            float4 v = a[qq];
            v.y += v.x; v.z += v.y; v.w += v.z;
            const float tot = v.w;
            float sfull = tot;
            #pragma unroll
            for (int d = 1; d < 64; d <<= 1) {
                float n = __shfl_up(sfull, d);
                if (lane >= d) sfull += n;
            }
            const float add = (sfull - tot) + carry;
            v.x += add; v.y += add; v.z += add; v.w += add;
            op[qq * 64 + lane] = v;
            carry += __shfl(sfull, 63);
        }
    }
}

extern "C" void kernel_launch(void* const* d_in, const int* in_sizes, int n_in,
                              void* d_out, int out_size, void* d_ws, size_t ws_size,
                              hipStream_t stream) {
    const float* in  = (const float*)d_in[0];
    float*       out = (float*)d_out;

    sgi_fused_kernel<<<dim3(Y_BLOCKS + X_BLOCKS), dim3(1024), 0, stream>>>(in, out);
}

// Round 12
// 436.409 us; speedup vs baseline: 1.0141x; 1.0141x over previous
//
#include <hip/hip_runtime.h>

#define IMG_W 1024
#define BATCH 32
#define NPIX (IMG_W * IMG_W)

#define Y_BLOCKS 512                 // 64-col stripes: 32*1024/64
#define X_BLOCKS 8192                // 4 rows per 256-thr block
#define TILE_R 32
#define TILE_C 64
#define N_TILES (IMG_W / TILE_R)     // 32

// 256-thread blocks. bid < Y_BLOCKS -> Y (height cumsum, ch1, LDS-transposed,
// double-buffered); else -> X (width cumsum, ch0, one wave per row).
__global__ __launch_bounds__(256) void sgi_fused_kernel(const float* __restrict__ in,
                                                        float* __restrict__ out) {
    __shared__ float tile[2][TILE_R][TILE_C];   // 2 x 8 KiB
    __shared__ float aux[4][TILE_C];            // 1 KiB

    const int bid = blockIdx.x;
    const int tid = threadIdx.x;

    if (bid < Y_BLOCKS) {
        // ---- Y: height cumsum (channel 1) -------------------------------
        const int b  = bid >> 4;                  // 16 stripes per image
        const int x0 = (bid & 15) * TILE_C;
        const float* ib = in  + (size_t)b * (2 * NPIX) + NPIX + x0;
        float*       ob = out + (size_t)b * (2 * NPIX) + NPIX + x0;

        // load/store float4 slots: f = tid and tid+256 of the 512-float4 tile
        const int f0 = tid,        r0 = f0 >> 4, c40 = f0 & 15;
        const int f1 = tid + 256,  r1 = f1 >> 4, c41 = f1 & 15;
        // scan role: column c, quarter q (8 rows)
        const int c = tid & 63;
        const int q = tid >> 6;

        float carry = 0.0f;

        // prologue: stage tile 0 into buf 0
        {
            float4 g0 = ((const float4*)(ib + (size_t)r0 * IMG_W))[c40];
            float4 g1 = ((const float4*)(ib + (size_t)r1 * IMG_W))[c41];
            ((float4*)tile[0])[f0] = g0;
            ((float4*)tile[0])[f1] = g1;
        }

        for (int t = 0; t < N_TILES; ++t) {
            const int cur = t & 1, nxt = cur ^ 1;
            const size_t rowbase = (size_t)t * TILE_R;

            // issue next tile's global loads early (hide under scan phases)
            float4 g0, g1;
            if (t + 1 < N_TILES) {
                const size_t nb = rowbase + TILE_R;
                g0 = ((const float4*)(ib + (nb + r0) * IMG_W))[c40];
                g1 = ((const float4*)(ib + (nb + r1) * IMG_W))[c41];
            }

            __syncthreads();                     // (i) cur fully staged
            // scan 8 rows of column c (2-way LDS aliasing: free)
            float p[8];
            float run = 0.0f;
            #pragma unroll
            for (int i = 0; i < 8; ++i) { run += tile[cur][q * 8 + i][c]; p[i] = run; }
            aux[q][c] = run;
            __syncthreads();                     // (ii) aux ready

            const float a0 = aux[0][c], a1 = aux[1][c], a2 = aux[2][c], a3 = aux[3][c];
            float qoff = carry;
            if (q > 0) qoff += a0;
            if (q > 1) qoff += a1;
            if (q > 2) qoff += a2;
            carry += a0 + a1 + a2 + a3;
            #pragma unroll
            for (int i = 0; i < 8; ++i) tile[cur][q * 8 + i][c] = p[i] + qoff;
            __syncthreads();                     // (iii) writeback done

            // store cur tile (coalesced), then stage next into nxt buffer
            ((float4*)(ob + (rowbase + r0) * IMG_W))[c40] = ((const float4*)tile[cur])[f0];
            ((float4*)(ob + (rowbase + r1) * IMG_W))[c41] = ((const float4*)tile[cur])[f1];
            if (t + 1 < N_TILES) {
                ((float4*)tile[nxt])[f0] = g0;
                ((float4*)tile[nxt])[f1] = g1;
            }
        }
    } else {
        // ---- X: width cumsum (channel 0), one wave per row --------------
        const int xbid = bid - Y_BLOCKS;         // 0..8191
        const int lane = tid & 63;
        const int wave = tid >> 6;
        const int row  = xbid * 4 + wave;        // 0 .. BATCH*IMG_W-1
        const int b    = row >> 10;
        const int y    = row & (IMG_W - 1);

        const size_t base = (size_t)b * (2 * NPIX) + (size_t)y * IMG_W;
        const float4* ip = (const float4*)(in + base);
        float4*       op = (float4*)(out + base);

        float4 a[4];
        #pragma unroll
        for (int qq = 0; qq < 4; ++qq) a[qq] = ip[qq * 64 + lane];

        float carry = 0.0f;
        #pragma unroll
        for (int qq = 0; qq < 4; ++qq) {
            float4 v = a[qq];
            v.y += v.x; v.z += v.y; v.w += v.z;
            const float tot = v.w;
            float sfull = tot;
            #pragma unroll
            for (int d = 1; d < 64; d <<= 1) {
                float n = __shfl_up(sfull, d);
                if (lane >= d) sfull += n;
            }
            const float add = (sfull - tot) + carry;
            v.x += add; v.y += add; v.z += add; v.w += add;
            op[qq * 64 + lane] = v;
            carry += __shfl(sfull, 63);
        }
    }
}

extern "C" void kernel_launch(void* const* d_in, const int* in_sizes, int n_in,
                              void* d_out, int out_size, void* d_ws, size_t ws_size,
                              hipStream_t stream) {
    const float* in  = (const float*)d_in[0];
    float*       out = (float*)d_out;

    sgi_fused_kernel<<<dim3(Y_BLOCKS + X_BLOCKS), dim3(256), 0, stream>>>(in, out);
}